// Round 1
// baseline (1272.567 us; speedup 1.0000x reference)
//
#include <hip/hip_runtime.h>
#include <cmath>

#define B_   128
#define S_   2048
#define D_   512
#define NA   3          // agents (A); A+1 logits
#define TS   64         // S-tile rows per block
#define CH   16         // pooling chunks over S
#define ROWS_PER_CH (S_/CH)   // 128

typedef __bf16 bf16x8 __attribute__((ext_vector_type(8)));
typedef float  f32x4  __attribute__((ext_vector_type(4)));

// ---------------- workspace layout (bytes) ----------------
// [0)          w1 bf16:  3*512*512*2 = 1572864
// [1572864)    w2 bf16:  1572864
// [3145728)    pool partials: 128*16*512*4 = 4194304
// [7340032)    route:    128*4
// total ~7.34 MB

// ---------- kernel: fp32 -> bf16 weight conversion ----------
__global__ void k_wconv(const float* __restrict__ w1, const float* __restrict__ w2,
                        __bf16* __restrict__ w1b, __bf16* __restrict__ w2b, int n) {
    int i = blockIdx.x * 256 + threadIdx.x;
    if (i < n) {
        w1b[i] = (__bf16)w1[i];
        w2b[i] = (__bf16)w2[i];
    }
}

// ---------- kernel: partial mean-pool over S chunks ----------
__global__ void k_pool1(const float* __restrict__ h, float* __restrict__ part) {
    int c = blockIdx.x;          // chunk
    int b = blockIdx.y;          // batch
    int t = threadIdx.x;         // 0..255, two columns each (float2)
    const float2* p = (const float2*)(h + ((size_t)b * S_ + (size_t)c * ROWS_PER_CH) * D_) + t;
    float ax = 0.f, ay = 0.f;
    #pragma unroll 4
    for (int s = 0; s < ROWS_PER_CH; ++s) {
        float2 v = p[(size_t)s * (D_ / 2)];
        ax += v.x; ay += v.y;
    }
    float2 o; o.x = ax; o.y = ay;
    ((float2*)(part + ((size_t)b * CH + c) * D_))[t] = o;
}

// ---------- kernel: finalize pooling, logits, argmax ----------
__global__ void k_route(const float* __restrict__ part, const float* __restrict__ selw,
                        const float* __restrict__ selb, int* __restrict__ route) {
    int b = blockIdx.x;
    int t = threadIdx.x;         // 64 threads = 1 wave
    float lg[NA + 1] = {0.f, 0.f, 0.f, 0.f};
    #pragma unroll
    for (int i = 0; i < D_ / 64; ++i) {
        int d = t + 64 * i;
        float s = 0.f;
        #pragma unroll
        for (int c = 0; c < CH; ++c) s += part[((size_t)b * CH + c) * D_ + d];
        float pooled = s * (1.0f / S_);
        #pragma unroll
        for (int j = 0; j <= NA; ++j) lg[j] += pooled * selw[j * D_ + d];
    }
    #pragma unroll
    for (int off = 32; off > 0; off >>= 1) {
        #pragma unroll
        for (int j = 0; j <= NA; ++j) lg[j] += __shfl_down(lg[j], off);
    }
    if (t == 0) {
        float best = lg[0] + selb[0];
        int aid = 0;
        #pragma unroll
        for (int j = 1; j <= NA; ++j) {
            float v = lg[j] + selb[j];
            if (v > best) { best = v; aid = j; }   // strict > == first-max (numpy argmax)
        }
        route[b] = aid;
    }
}

// ---------- main fused kernel ----------
// block = 256 threads (4 waves); grid = (S/TS, B)
// LDS: 64x512 bf16, swizzled in 16B units: unit(row,u) stored at row*64 + (u^row)
__global__ __launch_bounds__(256, 2) void k_main(
    const float* __restrict__ h, const __bf16* __restrict__ w1b,
    const __bf16* __restrict__ w2b, const int* __restrict__ route,
    float* __restrict__ out)
{
    const int st  = blockIdx.x;            // s-tile index, 0..31
    const int b   = blockIdx.y;            // batch
    const int s0  = st * TS;
    const int tid = threadIdx.x;
    const size_t tile_off = ((size_t)b * S_ + s0) * D_;

    const int aid = route[b];
    if (aid == 0) {
        // no-op agent: exact fp32 copy
        const float4* src = (const float4*)(h + tile_off);
        float4*       dst = (float4*)(out + tile_off);
        for (int i = tid; i < TS * D_ / 4; i += 256) dst[i] = src[i];
        return;
    }
    const int widx = aid - 1;
    const __bf16* W1 = w1b + (size_t)widx * D_ * D_;
    const __bf16* W2 = w2b + (size_t)widx * D_ * D_;

    __shared__ __bf16 lds[TS * D_];        // 64 KB

    // ---- stage 0: h tile fp32 -> bf16 -> LDS (swizzled) ----
    for (int i = tid; i < TS * D_ / 8; i += 256) {
        int row = i >> 6;                  // 64 16B-units per row
        int u   = i & 63;
        const float* src = h + tile_off + (size_t)row * D_ + u * 8;
        float4 f0 = *(const float4*)(src);
        float4 f1 = *(const float4*)(src + 4);
        bf16x8 v;
        v[0] = (__bf16)f0.x; v[1] = (__bf16)f0.y; v[2] = (__bf16)f0.z; v[3] = (__bf16)f0.w;
        v[4] = (__bf16)f1.x; v[5] = (__bf16)f1.y; v[6] = (__bf16)f1.z; v[7] = (__bf16)f1.w;
        *(bf16x8*)&lds[((size_t)row * 64 + (u ^ row)) * 8] = v;
    }
    __syncthreads();

    const int lane = tid & 63;
    const int wv   = tid >> 6;             // wave id 0..3
    const int nb   = wv * 128;             // this wave's N-slice base (o for stage1, e for stage2)
    const int l15  = lane & 15;
    const int quad = lane >> 4;

    f32x4 acc[4][8];
    #pragma unroll
    for (int mt = 0; mt < 4; ++mt)
        #pragma unroll
        for (int nt = 0; nt < 8; ++nt) acc[mt][nt] = (f32x4){0.f, 0.f, 0.f, 0.f};

    // ---- stage 1: hid = h @ W1^T  (M=64 rows, N=128 per wave, K=512) ----
    for (int kt = 0; kt < D_ / 32; ++kt) {
        const int kb = kt * 32;
        bf16x8 a[4];
        #pragma unroll
        for (int mt = 0; mt < 4; ++mt) {
            int row = mt * 16 + l15;
            int u   = (kb >> 3) + quad;
            a[mt] = *(const bf16x8*)&lds[((size_t)row * 64 + (u ^ row)) * 8];
        }
        bf16x8 bb[8];
        #pragma unroll
        for (int nt = 0; nt < 8; ++nt) {
            int o = nb + nt * 16 + l15;
            bb[nt] = *(const bf16x8*)(W1 + (size_t)o * D_ + kb + quad * 8);
        }
        #pragma unroll
        for (int mt = 0; mt < 4; ++mt)
            #pragma unroll
            for (int nt = 0; nt < 8; ++nt)
                acc[mt][nt] = __builtin_amdgcn_mfma_f32_16x16x32_bf16(a[mt], bb[nt], acc[mt][nt], 0, 0, 0);
    }
    __syncthreads();   // all A-reads of h staging done

    // ---- gelu(hid) -> bf16 -> LDS (overwrites h staging) ----
    #pragma unroll
    for (int mt = 0; mt < 4; ++mt) {
        #pragma unroll
        for (int nt = 0; nt < 8; ++nt) {
            #pragma unroll
            for (int r = 0; r < 4; ++r) {
                int row = mt * 16 + quad * 4 + r;
                int col = nb + nt * 16 + l15;
                float x = acc[mt][nt][r];
                float g = 0.5f * x * (1.0f + erff(x * 0.70710678118654752f));
                lds[((size_t)row * 64 + ((col >> 3) ^ row)) * 8 + (col & 7)] = (__bf16)g;
            }
        }
    }
    __syncthreads();

    // ---- stage 2: delta = hid @ W2^T ----
    #pragma unroll
    for (int mt = 0; mt < 4; ++mt)
        #pragma unroll
        for (int nt = 0; nt < 8; ++nt) acc[mt][nt] = (f32x4){0.f, 0.f, 0.f, 0.f};

    for (int kt = 0; kt < D_ / 32; ++kt) {
        const int kb = kt * 32;
        bf16x8 a[4];
        #pragma unroll
        for (int mt = 0; mt < 4; ++mt) {
            int row = mt * 16 + l15;
            int u   = (kb >> 3) + quad;
            a[mt] = *(const bf16x8*)&lds[((size_t)row * 64 + (u ^ row)) * 8];
        }
        bf16x8 bb[8];
        #pragma unroll
        for (int nt = 0; nt < 8; ++nt) {
            int e = nb + nt * 16 + l15;
            bb[nt] = *(const bf16x8*)(W2 + (size_t)e * D_ + kb + quad * 8);
        }
        #pragma unroll
        for (int mt = 0; mt < 4; ++mt)
            #pragma unroll
            for (int nt = 0; nt < 8; ++nt)
                acc[mt][nt] = __builtin_amdgcn_mfma_f32_16x16x32_bf16(a[mt], bb[nt], acc[mt][nt], 0, 0, 0);
    }

    // ---- epilogue: out = h (fp32, exact) + delta ----
    #pragma unroll
    for (int mt = 0; mt < 4; ++mt) {
        #pragma unroll
        for (int nt = 0; nt < 8; ++nt) {
            #pragma unroll
            for (int r = 0; r < 4; ++r) {
                int row = mt * 16 + quad * 4 + r;
                int col = nb + nt * 16 + l15;
                size_t gi = tile_off + (size_t)row * D_ + col;
                out[gi] = h[gi] + acc[mt][nt][r];
            }
        }
    }
}

extern "C" void kernel_launch(void* const* d_in, const int* in_sizes, int n_in,
                              void* d_out, int out_size, void* d_ws, size_t ws_size,
                              hipStream_t stream) {
    const float* h    = (const float*)d_in[0];   // [B,S,D]
    const float* selw = (const float*)d_in[1];   // [A+1,D]
    const float* selb = (const float*)d_in[2];   // [A+1]
    const float* w1   = (const float*)d_in[3];   // [A,D,D]
    const float* w2   = (const float*)d_in[4];   // [A,D,D]
    float* out        = (float*)d_out;           // [B,S,D]

    char* ws = (char*)d_ws;
    __bf16* w1b  = (__bf16*)(ws);
    __bf16* w2b  = (__bf16*)(ws + 1572864);
    float*  part = (float*)(ws + 3145728);
    int*    route = (int*)(ws + 7340032);

    const int nW = NA * D_ * D_;                 // 786432
    k_wconv<<<(nW + 255) / 256, 256, 0, stream>>>(w1, w2, w1b, w2b, nW);
    k_pool1<<<dim3(CH, B_), 256, 0, stream>>>(h, part);
    k_route<<<B_, 64, 0, stream>>>(part, selw, selb, route);
    k_main<<<dim3(S_ / TS, B_), 256, 0, stream>>>(h, w1b, w2b, route, out);
}